// Round 7
// baseline (152.289 us; speedup 1.0000x reference)
//
#include <hip/hip_runtime.h>
#include <hip/hip_bf16.h>
#include <math.h>

#define BB 8
#define HH 512
#define WW 512
#define NPIX (BB * HH * WW)        // 2097152
#define HWPIX (HH * WW)            // 262144 = 2^18
#define PBUD 1048576               // P
#define RAD 7                      // 15//2
#define NB (NPIX / 256)            // 8192 rank blocks of 256 pixels
#define NMLP (NPIX / 128)          // 16384 MLP blocks of 128 pixels

typedef __attribute__((ext_vector_type(4))) float f32x4;
typedef __attribute__((ext_vector_type(8))) short short8;
typedef __attribute__((ext_vector_type(2))) unsigned int u32x2;
typedef __attribute__((ext_vector_type(4))) unsigned int u32x4;

__device__ __forceinline__ unsigned short f2bf(float f) {
    unsigned int u = __float_as_uint(f);
    unsigned int r = (u + 0x7fffu + ((u >> 16) & 1u)) >> 16;   // RNE
    return (unsigned short)r;
}

// packed f32 pair -> bf16x2 (compiler emits v_cvt_pk_bf16_f32; m240: use casts, not asm)
__device__ __forceinline__ unsigned int pkbf(float a, float b) {
    __hip_bfloat162 h = __float22bfloat162_rn(make_float2(a, b));
    return *(unsigned int*)&h;
}

// ---- K0: weight prep ---------------------------------------------------------
// w2f: bf16 B-fragments of W2, exact MFMA lane order (verified round 5):
//   w2f[((jc*4+ks)*64+l)*8+e] = W2[k][j], j=jc*16+(l&15), k=ks*32+((l>>4)&3)*8+e
// w1f: bf16 A-fragments of W1'^T (K padded 5->32; row 4 of W1' = b1, rest 0):
//   w1f[(fi*64+l)*8+e] = W1'[k][j], j=fi*16+(l&15), k=((l>>4)&3)*8+e
__global__ void k_prep(const float* __restrict__ w2, const float* __restrict__ w1,
                       const float* __restrict__ b1,
                       unsigned short* __restrict__ w2f, unsigned short* __restrict__ w1f) {
    int i = blockIdx.x * 256 + threadIdx.x;   // 20480 threads
    if (i < 16384) {
        int e  = i & 7;
        int l  = (i >> 3) & 63;
        int ks = (i >> 9) & 3;
        int jc = i >> 11;
        int j = jc * 16 + (l & 15);
        int k = ks * 32 + ((l >> 4) & 3) * 8 + e;
        w2f[i] = f2bf(w2[k * 128 + j]);
    } else {
        int i2 = i - 16384;                   // 4096 elements
        int e  = i2 & 7;
        int l  = (i2 >> 3) & 63;
        int fi = i2 >> 9;                     // 0..7
        int j = fi * 16 + (l & 15);
        int k = ((l >> 4) & 3) * 8 + e;       // 0..31
        float v = (k < 4) ? w1[k * 128 + j] : ((k == 4) ? b1[j] : 0.0f);
        w1f[i2] = f2bf(v);
    }
}

// ---------------- K1: mask + horizontal dilate --------------------------------
__global__ void k_rowdil(const float* __restrict__ lr, unsigned char* __restrict__ rowdil) {
    int p = blockIdx.x * 256 + threadIdx.x;
    int w = p & (WW - 1);
    int row0 = p - w;
    int lo = w - RAD; if (lo < 0) lo = 0;
    int hi = w + RAD; if (hi > WW - 1) hi = WW - 1;
    unsigned char any = 0;
    for (int x = lo; x <= hi; ++x) {
        float v = lr[row0 + x];
        any |= (unsigned char)(v > 0.01f && v < 0.99f);
    }
    rowdil[p] = any;
}

// ------- K2: vertical dilate + per-256-block count + intra-block rank byte ----
__global__ void k_coldil(const unsigned char* __restrict__ rowdil,
                         unsigned char* __restrict__ dm,
                         unsigned char* __restrict__ rankb,
                         int* __restrict__ gsum) {
    int p = blockIdx.x * 256 + threadIdx.x;
    int h = (p >> 9) & (HH - 1);
    int lo = h - RAD; if (lo < 0) lo = 0;
    int hi = h + RAD; if (hi > HH - 1) hi = HH - 1;
    lo -= h; hi -= h;
    unsigned char any = 0;
    for (int d = lo; d <= hi; ++d) any |= rowdil[p + d * WW];
    dm[p] = any;

    unsigned long long bal = __ballot(any != 0);
    __shared__ int wsum[4];
    int lane = threadIdx.x & 63;
    int wid  = threadIdx.x >> 6;
    if (lane == 0) wsum[wid] = __popcll(bal);
    __syncthreads();
    int pre = __popcll(bal & ((1ull << lane) - 1ull));
    int woff = 0;
    for (int i = 0; i < wid; ++i) woff += wsum[i];
    rankb[p] = (unsigned char)(woff + pre);
    if (threadIdx.x == 0) gsum[blockIdx.x] = wsum[0] + wsum[1] + wsum[2] + wsum[3];
}

// ---------------- K3: exclusive scan of 8192 block counts (one block) ---------
__global__ void k_scan(const int* __restrict__ gsum, int* __restrict__ goff) {
    __shared__ int tsum[1024];
    int t = threadIdx.x;
    int base = t * 8;
    int v[8];
    int s = 0;
#pragma unroll
    for (int i = 0; i < 8; ++i) { v[i] = gsum[base + i]; s += v[i]; }
    tsum[t] = s;
    __syncthreads();
    for (int off = 1; off < 1024; off <<= 1) {
        int x = tsum[t];
        int y = (t >= off) ? tsum[t - off] : 0;
        __syncthreads();
        tsum[t] = x + y;
        __syncthreads();
    }
    int run = (t == 0) ? 0 : tsum[t - 1];
#pragma unroll
    for (int i = 0; i < 8; ++i) { goff[base + i] = run; run += v[i]; }
}

// ---------------- K4: full-MFMA MLP over 128-pixel tiles ----------------------
// LDS: [0,32768)        H1 tile, 128 px-rows x 128 j (256B rows), swz ^(px&15)<<4
//      [32768,43008)    X'^T staging: 128 px-rows x 80B (k slots 0..4 = x0..x3,1)
// L1: H1^T[j][px] = W1'^T @ X'^T via MFMA (K=32, bias in k=4); D written straight
//     into the H1 layout phase 2 reads. L2: verified round-5 path, b2 in acc init.
__global__ __launch_bounds__(256, 3)
void k_mlp(const float* __restrict__ image, const float* __restrict__ lr,
           const unsigned short* __restrict__ w1f, const unsigned short* __restrict__ w2f,
           const float* __restrict__ b2, const float* __restrict__ w3,
           const float* __restrict__ b3,
           const unsigned char* __restrict__ dm, const unsigned char* __restrict__ rankb,
           const int* __restrict__ goff, float* __restrict__ out) {
    __shared__ __align__(16) char lds[43008];
    __shared__ int s_any;
    int g  = blockIdx.x;
    int p0 = g * 128;
    int t  = threadIdx.x;

    // ---- phase 0: selection + any ----
    if (t == 0) s_any = 0;
    __syncthreads();
    float lrv0 = 0.f;
    if (t < 128) {
        int p = p0 + t;
        lrv0 = lr[p];
        if (dm[p] && (goff[p >> 8] + (int)rankb[p] < PBUD)) s_any = 1;
    }
    __syncthreads();
    if (!s_any) {
        if (t < 128) out[p0 + t] = lrv0;
        return;
    }

    // ---- phase 0.5: stage X'^T rows (bf16) ----
    if (t < 128) {
        int p = p0 + t;
        size_t bimg = (size_t)(p >> 18) * 3 * HWPIX + (p & (HWPIX - 1));
        float x0 = image[bimg];
        float x1 = image[bimg + HWPIX];
        float x2 = image[bimg + 2 * HWPIX];
        float x3 = 2.0f * lrv0 - 1.0f;
        char* xr = lds + 32768 + t * 80;
        u32x4 d0 = { pkbf(x0, x1), pkbf(x2, x3), pkbf(1.0f, 0.0f), 0u };
        u32x4 z  = { 0u, 0u, 0u, 0u };
        *(u32x4*)(xr)      = d0;
        *(u32x4*)(xr + 16) = z;
        *(u32x4*)(xr + 32) = z;
        *(u32x4*)(xr + 48) = z;
        *(u32x4*)(xr + 64) = z;
    }

    int w    = t >> 6;
    int l    = t & 63;
    int lr16 = l & 15;
    int lh   = (l >> 4) & 3;

    // L1 A-fragments (W1'^T), global fragment-ordered, L2-hot
    const short8* wf1 = (const short8*)w1f;
    short8 a1_0 = wf1[(w * 2 + 0) * 64 + l];
    short8 a1_1 = wf1[(w * 2 + 1) * 64 + l];
    __syncthreads();                        // X' visible

    // ---- phase 1: H1^T = W1'^T @ X'^T, relu, bf16 -> H1 LDS ----
#pragma unroll
    for (int jc = 0; jc < 8; ++jc) {
        int px = jc * 16 + lr16;
        short8 xb = *(const short8*)(lds + 32768 + px * 80 + lh * 16);
        f32x4 c0 = {0.f, 0.f, 0.f, 0.f};
        f32x4 c1 = {0.f, 0.f, 0.f, 0.f};
        c0 = __builtin_amdgcn_mfma_f32_16x16x32_bf16(a1_0, xb, c0, 0, 0, 0);
        c1 = __builtin_amdgcn_mfma_f32_16x16x32_bf16(a1_1, xb, c1, 0, 0, 0);
        int swz = (px & 15) << 4;
        {   // tile fi = w*2: j0 = fi*16 + lh*4
            int j0 = (w * 2 + 0) * 16 + lh * 4;
            u32x2 u = { pkbf(fmaxf(c0[0], 0.f), fmaxf(c0[1], 0.f)),
                        pkbf(fmaxf(c0[2], 0.f), fmaxf(c0[3], 0.f)) };
            *(u32x2*)(lds + (((px << 8) | (j0 << 1)) ^ swz)) = u;
        }
        {   // tile fi = w*2+1
            int j1 = (w * 2 + 1) * 16 + lh * 4;
            u32x2 u = { pkbf(fmaxf(c1[0], 0.f), fmaxf(c1[1], 0.f)),
                        pkbf(fmaxf(c1[2], 0.f), fmaxf(c1[3], 0.f)) };
            *(u32x2*)(lds + (((px << 8) | (j1 << 1)) ^ swz)) = u;
        }
    }
    __syncthreads();

    // ---- phase 2: wave w computes px rows [w*32, w*32+32) x all 128 j ----
    int rowbase = w * 32;
    short8 af[2][4];
#pragma unroll
    for (int ks = 0; ks < 4; ++ks) {
#pragma unroll
        for (int mt = 0; mt < 2; ++mt) {
            int row = rowbase + mt * 16 + lr16;
            int a = (((row << 8) | (ks << 6) | (lh << 4))) ^ ((row & 15) << 4);
            af[mt][ks] = *(const short8*)(lds + a);
        }
    }

    float b2v[8], w3v[8];
#pragma unroll
    for (int jc = 0; jc < 8; ++jc) {
        int col = jc * 16 + lr16;
        b2v[jc] = b2[col];
        w3v[jc] = w3[col];
    }
    float b3v = b3[0];

    f32x4 acc[2][8];
#pragma unroll
    for (int mt = 0; mt < 2; ++mt)
#pragma unroll
        for (int jc = 0; jc < 8; ++jc)
            acc[mt][jc] = (f32x4){b2v[jc], b2v[jc], b2v[jc], b2v[jc]};  // bias folded

    const short8* wf = (const short8*)w2f;
#pragma unroll
    for (int jc = 0; jc < 8; ++jc) {
        short8 bf[4];
#pragma unroll
        for (int ks = 0; ks < 4; ++ks) bf[ks] = wf[(jc * 4 + ks) * 64 + l];  // coalesced, L2-hot
#pragma unroll
        for (int ks = 0; ks < 4; ++ks) {
            acc[0][jc] = __builtin_amdgcn_mfma_f32_16x16x32_bf16(af[0][ks], bf[ks], acc[0][jc], 0, 0, 0);
            acc[1][jc] = __builtin_amdgcn_mfma_f32_16x16x32_bf16(af[1][ks], bf[ks], acc[1][jc], 0, 0, 0);
        }
    }

    // ---- epilogue: relu + dot(w3) reduce + sigmoid + select ----
#pragma unroll
    for (int mt = 0; mt < 2; ++mt) {
#pragma unroll
        for (int r = 0; r < 4; ++r) {
            int row = rowbase + mt * 16 + lh * 4 + r;   // C/D: row = (lane>>4)*4 + reg
            float part = 0.f;
#pragma unroll
            for (int jc = 0; jc < 8; ++jc)
                part += fmaxf(acc[mt][jc][r], 0.f) * w3v[jc];
            part += __shfl_xor(part, 1);
            part += __shfl_xor(part, 2);
            part += __shfl_xor(part, 4);
            part += __shfl_xor(part, 8);
            if (lr16 == 0) {
                int p = p0 + row;
                float lrv = lr[p];
                bool s = dm[p] && (goff[p >> 8] + (int)rankb[p] < PBUD);
                float logit = b3v + part;
                out[p] = s ? (1.0f / (1.0f + __expf(-logit))) : lrv;
            }
        }
    }
}

// ---------------- launcher ----------------------------------------------------
extern "C" void kernel_launch(void* const* d_in, const int* in_sizes, int n_in,
                              void* d_out, int out_size, void* d_ws, size_t ws_size,
                              hipStream_t stream) {
    const float* image = (const float*)d_in[0];
    const float* lr    = (const float*)d_in[1];
    const float* w1    = (const float*)d_in[2];
    const float* b1    = (const float*)d_in[3];
    const float* w2    = (const float*)d_in[4];
    const float* b2    = (const float*)d_in[5];
    const float* w3    = (const float*)d_in[6];
    const float* b3    = (const float*)d_in[7];
    float* out = (float*)d_out;

    char* ws = (char*)d_ws;
    unsigned char* rowdil = (unsigned char*)ws;                         // NPIX
    unsigned char* dm     = (unsigned char*)(ws + (size_t)NPIX);        // NPIX
    unsigned char* rankb  = (unsigned char*)(ws + 2 * (size_t)NPIX);    // NPIX
    int* gsum             = (int*)(ws + 3 * (size_t)NPIX);              // NB
    int* goff             = (int*)(ws + 3 * (size_t)NPIX + NB * 4);     // NB
    unsigned short* w2f   = (unsigned short*)(ws + 3 * (size_t)NPIX + 2 * NB * 4); // 16384 bf16
    unsigned short* w1f   = w2f + 16384;                                           // 4096 bf16

    k_prep  <<<80, 256, 0, stream>>>(w2, w1, b1, w2f, w1f);
    k_rowdil<<<NPIX / 256, 256, 0, stream>>>(lr, rowdil);
    k_coldil<<<NB, 256, 0, stream>>>(rowdil, dm, rankb, gsum);
    k_scan  <<<1, 1024, 0, stream>>>(gsum, goff);
    k_mlp   <<<NMLP, 256, 0, stream>>>(image, lr, w1f, w2f, b2, w3, b3,
                                       dm, rankb, goff, out);
}